// Round 1
// baseline (554.761 us; speedup 1.0000x reference)
//
#include <hip/hip_runtime.h>

#define TILE_M 64
#define TILE_K 32
#define NEXP 64

// ---------------- Kernel A: gate GEMM, f64 accumulate ----------------
// S[token][e] = sum_h X[token][h] * W[e][h]
// 256 threads, 64x64 tile, BK=32, 4x4 micro-tile, XOR-swizzled double2 LDS.
__global__ __launch_bounds__(256) void gemm_scores_f64(
    const float* __restrict__ X, const float* __restrict__ W,
    float* __restrict__ S, int H) {
  __shared__ double2 As2[TILE_M][TILE_K / 2];
  __shared__ double2 Bs2[NEXP][TILE_K / 2];
  const int tid = threadIdx.x;
  const int row0 = blockIdx.x * TILE_M;
  const int tr = (tid >> 4) << 2;   // token offset within tile (0..60, step 4)
  const int tc = (tid & 15) << 2;   // expert offset within tile
  const int swz_a = (tr >> 2) & 15; // constant per thread
  const int swz_b = (tc >> 2) & 15;
  double acc[4][4] = {};

  for (int k0 = 0; k0 < H; k0 += TILE_K) {
    __syncthreads();
    // stage A (64 tokens x 32 k) and B (64 experts x 32 k), f32->f64
#pragma unroll
    for (int i = 0; i < 2; ++i) {
      const int idx = tid + (i << 8);  // 0..511
      const int r = idx >> 3;          // 0..63
      const int c4 = idx & 7;          // float4 column
      const int sw = (r >> 2) & 15;
      const float4 va = *reinterpret_cast<const float4*>(
          X + (size_t)(row0 + r) * H + k0 + (c4 << 2));
      As2[r][(c4 * 2) ^ sw]     = make_double2((double)va.x, (double)va.y);
      As2[r][(c4 * 2 + 1) ^ sw] = make_double2((double)va.z, (double)va.w);
      const float4 vb = *reinterpret_cast<const float4*>(
          W + (size_t)r * H + k0 + (c4 << 2));
      Bs2[r][(c4 * 2) ^ sw]     = make_double2((double)vb.x, (double)vb.y);
      Bs2[r][(c4 * 2 + 1) ^ sw] = make_double2((double)vb.z, (double)vb.w);
    }
    __syncthreads();
#pragma unroll
    for (int ku = 0; ku < TILE_K / 2; ++ku) {
      double2 a[4], b[4];
#pragma unroll
      for (int i = 0; i < 4; ++i) a[i] = As2[tr + i][ku ^ swz_a];
#pragma unroll
      for (int j = 0; j < 4; ++j) b[j] = Bs2[tc + j][ku ^ swz_b];
#pragma unroll
      for (int i = 0; i < 4; ++i)
#pragma unroll
        for (int j = 0; j < 4; ++j) {
          acc[i][j] = fma(a[i].x, b[j].x, acc[i][j]);
          acc[i][j] = fma(a[i].y, b[j].y, acc[i][j]);
        }
    }
  }
#pragma unroll
  for (int i = 0; i < 4; ++i) {
    float4 out;
    out.x = (float)acc[i][0];
    out.y = (float)acc[i][1];
    out.z = (float)acc[i][2];
    out.w = (float)acc[i][3];
    *reinterpret_cast<float4*>(S + (size_t)(row0 + tr + i) * NEXP + tc) = out;
  }
}

// ------------- Kernel B: softmax (in-place) + top-K + histogram -------------
// One wave per token (lane = expert). 4 waves/block, 16 tokens per wave.
__global__ __launch_bounds__(256) void softmax_topk_hist(
    float* __restrict__ S, const float* __restrict__ bias,
    float* __restrict__ wout, float* __restrict__ iout,
    float* __restrict__ gcount, int K) {
  __shared__ int hist[NEXP];
  const int tid = threadIdx.x;
  if (tid < NEXP) hist[tid] = 0;
  __syncthreads();
  const int lane = tid & 63;
  const int wave = tid >> 6;
  const double b = (double)bias[lane];
  const int t0 = blockIdx.x * 64 + wave * 16;

  for (int tt = 0; tt < 16; ++tt) {
    const int t = t0 + tt;
    const size_t base = (size_t)t * NEXP;
    double s = (double)S[base + lane] + b;
    // wave max
    double m = s;
#pragma unroll
    for (int off = 32; off >= 1; off >>= 1) {
      double o = __shfl_xor(m, off);
      m = fmax(m, o);
    }
    double e = exp(s - m);
    double sum = e;
#pragma unroll
    for (int off = 32; off >= 1; off >>= 1) sum += __shfl_xor(sum, off);
    const double p = e / sum;
    S[base + lane] = (float)p;

    // iterative top-K with lowest-index tie-break (matches lax.top_k)
    double w = p;
    double rv = 0.0;
    int ri = 0;
    for (int r = 0; r < K; ++r) {
      double v = w;
      int ii = lane;
#pragma unroll
      for (int off = 32; off >= 1; off >>= 1) {
        double ov = __shfl_xor(v, off);
        int oi = __shfl_xor(ii, off);
        if (ov > v || (ov == v && oi < ii)) { v = ov; ii = oi; }
      }
      if (lane == r) { rv = v; ri = ii; }
      if (lane == ii) w = -1.0;  // remove winner (probs are >= 0)
      if (lane == 0) atomicAdd(&hist[ii], 1);
    }
    if (lane < K) {
      wout[(size_t)t * K + lane] = (float)rv;
      iout[(size_t)t * K + lane] = (float)ri;  // index as float value
    }
  }
  __syncthreads();
  if (tid < NEXP) atomicAdd(&gcount[tid], (float)hist[tid]);
}

// ------------- Kernel C: bias update (in place over count buffer) -------------
__global__ void bias_update(float* __restrict__ bout,
                            const float* __restrict__ bias, float tpe) {
  const int e = threadIdx.x;
  const float c = bout[e];
  const float d = c - tpe;
  const float sg = (d > 0.f) ? 1.f : ((d < 0.f) ? -1.f : 0.f);
  bout[e] = bias[e] + 0.01f * sg;
}

extern "C" void kernel_launch(void* const* d_in, const int* in_sizes, int n_in,
                              void* d_out, int out_size, void* d_ws, size_t ws_size,
                              hipStream_t stream) {
  const float* x = (const float*)d_in[0];
  const float* w = (const float*)d_in[1];
  const float* bias = (const float*)d_in[2];
  const int E = in_sizes[2];                      // 64
  const int H = in_sizes[1] / E;                  // 4096
  const long long N = (long long)in_sizes[0] / H; // 32768 tokens
  const int K = (int)(((long long)out_size - N * E - E) / (2 * N)); // 8

  float* S = (float*)d_out;                   // [N][E] probs (scores output)
  float* wout = S + (size_t)N * E;            // [N][K] expert_weights
  float* iout = wout + (size_t)N * K;         // [N][K] expert_indices (as float)
  float* bout = iout + (size_t)N * K;         // [E]    new_expert_biases

  // bout doubles as the float token-count accumulator; zero it every launch.
  hipMemsetAsync(bout, 0, E * sizeof(float), stream);

  gemm_scores_f64<<<dim3((int)(N / TILE_M)), dim3(256), 0, stream>>>(x, w, S, H);
  softmax_topk_hist<<<dim3((int)(N / 64)), dim3(256), 0, stream>>>(S, bias, wout,
                                                                   iout, bout, K);
  const float tpe = (float)((double)N * K / E);
  bias_update<<<dim3(1), dim3(E), 0, stream>>>(bout, bias, tpe);
}

// Round 2
// 499.132 us; speedup vs baseline: 1.1115x; 1.1115x over previous
//
#include <hip/hip_runtime.h>

#define BM 128
#define BK 32
#define NE 64
#define TAU 3e-4f

// async global->LDS, 16B per lane; LDS dest is wave-uniform base + lane*16
__device__ __forceinline__ void gld16(const float* g, float* l) {
  __builtin_amdgcn_global_load_lds(
      (const __attribute__((address_space(1))) void*)g,
      (__attribute__((address_space(3))) void*)l, 16, 0, 0);
}

// ---------------- Kernel A: gate GEMM, f32, gload_lds double-buffered -------
// S[token][e] = sum_h X[token][h] * W[e][h]; optional K-split via blockIdx.y.
// LDS tiles row-major [r][BK] with XOR quad swizzle: logical float4-col c4 is
// stored at phys quad c4 ^ (r&7). Staging achieves this by pre-swizzling the
// GLOBAL source address per lane while LDS dest stays linear (guide §5/m173).
__global__ __launch_bounds__(256, 2) void gemm_f32(
    const float* __restrict__ X, const float* __restrict__ W,
    float* __restrict__ out0, float* __restrict__ out1, int H, int ksplit) {
  __shared__ float As[2][BM * BK];
  __shared__ float Bs[2][NE * BK];
  const int tid = threadIdx.x;
  const int lane = tid & 63;
  const int wave = tid >> 6;
  const int row0 = blockIdx.x * BM;
  const int kseg = H / ksplit;
  const int kbeg = blockIdx.y * kseg;
  float* __restrict__ outp = blockIdx.y ? out1 : out0;

  // lane -> (row within 8-row group, swizzled source float4-col)
  const int lrow = lane >> 3;
  const int lc4 = (lane & 7) ^ (lrow & 7);  // rows are 8g+lrow, 8g%8==0

  const float* asrc[4];
  const float* bsrc[2];
#pragma unroll
  for (int o = 0; o < 4; ++o)
    asrc[o] = X + (size_t)(row0 + 8 * (wave * 4 + o) + lrow) * H + kbeg + lc4 * 4;
#pragma unroll
  for (int o = 0; o < 2; ++o)
    bsrc[o] = W + (size_t)(8 * (wave * 2 + o) + lrow) * H + kbeg + lc4 * 4;

#define ISSUE(t, buf)                                                        \
  do {                                                                       \
    const int kk_ = (t)*BK;                                                  \
    _Pragma("unroll") for (int o = 0; o < 4; ++o)                            \
        gld16(asrc[o] + kk_, &As[buf][(wave * 4 + o) * 256]);                \
    _Pragma("unroll") for (int o = 0; o < 2; ++o)                            \
        gld16(bsrc[o] + kk_, &Bs[buf][(wave * 2 + o) * 256]);                \
  } while (0)

  const int T = kseg / BK;
  float acc[8][4] = {};
  const int tcl = tid & 15;        // expert lane group: experts tcl+16j
  const int tr = (tid >> 4) * 8;   // 8 tokens per thread

  ISSUE(0, 0);
  for (int t = 0; t < T; ++t) {
    const int buf = t & 1;
    if (t + 1 < T) {
      ISSUE(t + 1, buf ^ 1);
      asm volatile("s_waitcnt vmcnt(6)" ::: "memory");  // tile t landed
    } else {
      asm volatile("s_waitcnt vmcnt(0)" ::: "memory");
    }
    __builtin_amdgcn_s_barrier();
    asm volatile("" ::: "memory");
#pragma unroll
    for (int q = 0; q < BK / 4; ++q) {
      float4 b4[4];
#pragma unroll
      for (int j = 0; j < 4; ++j) {
        const int er = tcl + 16 * j;  // er&7 == tcl&7
        b4[j] = *reinterpret_cast<const float4*>(
            &Bs[buf][er * BK + ((q ^ (tcl & 7)) << 2)]);
      }
#pragma unroll
      for (int i = 0; i < 8; ++i) {
        const float4 a4 = *reinterpret_cast<const float4*>(
            &As[buf][(tr + i) * BK + ((q ^ ((tr + i) & 7)) << 2)]);
#pragma unroll
        for (int j = 0; j < 4; ++j) {
          acc[i][j] = fmaf(a4.x, b4[j].x, acc[i][j]);
          acc[i][j] = fmaf(a4.y, b4[j].y, acc[i][j]);
          acc[i][j] = fmaf(a4.z, b4[j].z, acc[i][j]);
          acc[i][j] = fmaf(a4.w, b4[j].w, acc[i][j]);
        }
      }
    }
    asm volatile("" ::: "memory");
    __builtin_amdgcn_s_barrier();
    asm volatile("" ::: "memory");
  }
#pragma unroll
  for (int i = 0; i < 8; ++i)
#pragma unroll
    for (int j = 0; j < 4; ++j)
      outp[(size_t)(row0 + tr + i) * NE + tcl + 16 * j] = acc[i][j];
#undef ISSUE
}

// ------------- Kernel B: softmax + top-K + tiny-gap flagging ---------------
// One wave per token (lane = expert). Tokens whose top-9 raw-score adjacent
// gaps dip below TAU are deferred to the f64 recompute kernel.
__global__ __launch_bounds__(256) void softmax_topk(
    float* __restrict__ S, const float* __restrict__ P2, int use2,
    const float* __restrict__ bias, float* __restrict__ wout,
    float* __restrict__ iout, int* __restrict__ cnt, int* __restrict__ hist,
    int* __restrict__ list, int cap, int K) {
  __shared__ int hist_s[NE];
  const int tid = threadIdx.x;
  if (tid < NE) hist_s[tid] = 0;
  __syncthreads();
  const int lane = tid & 63;
  const int wave = tid >> 6;
  const float b = bias[lane];
  const int t0 = blockIdx.x * 64 + wave * 16;

  for (int tt = 0; tt < 16; ++tt) {
    const int t = t0 + tt;
    const size_t base = (size_t)t * NE;
    float s = S[base + lane] + b;
    if (use2) s += P2[base + lane];

    float m = s;
#pragma unroll
    for (int off = 32; off >= 1; off >>= 1) m = fmaxf(m, __shfl_xor(m, off));
    const float e = expf(s - m);
    float sum = e;
#pragma unroll
    for (int off = 32; off >= 1; off >>= 1) sum += __shfl_xor(sum, off);
    const float p = e / sum;

    // top-9 on raw biased score (ordering identical to probs), low-index ties
    float wsel = s;
    float rv = 0.f;
    int ri = 0;
    float prev = 0.f, mingap = 1e30f;
#pragma unroll
    for (int r = 0; r < 9; ++r) {
      float v = wsel;
      int ii = lane;
#pragma unroll
      for (int off = 32; off >= 1; off >>= 1) {
        const float ov = __shfl_xor(v, off);
        const int oi = __shfl_xor(ii, off);
        if (ov > v || (ov == v && oi < ii)) { v = ov; ii = oi; }
      }
      if (r > 0) mingap = fminf(mingap, prev - v);
      prev = v;
      const float pw = __shfl(p, ii);
      if (lane == r) { rv = pw; ri = ii; }
      if (lane == ii) wsel = -1e30f;
    }

    bool toC = false;
    if (mingap < TAU && cap > 0) {
      int pos = 0;
      if (lane == 0) pos = atomicAdd(cnt, 1);
      pos = __shfl(pos, 0);
      if (pos < cap) {
        if (lane == 0) list[pos] = t;
        toC = true;  // kernel C will produce all outputs for this token
      }
    }
    if (!toC) {
      S[base + lane] = p;
      if (lane < K) {
        wout[(size_t)t * K + lane] = rv;
        iout[(size_t)t * K + lane] = (float)ri;
        atomicAdd(&hist_s[ri], 1);
      }
    }
  }
  __syncthreads();
  if (tid < NE) atomicAdd(&hist[tid], hist_s[tid]);
}

// ------------- Kernel C: f64 recompute for flagged (near-tie) tokens --------
__global__ __launch_bounds__(256) void recompute_f64(
    const float* __restrict__ X, const float* __restrict__ W,
    const float* __restrict__ bias, float* __restrict__ S,
    float* __restrict__ wout, float* __restrict__ iout,
    const int* __restrict__ cnt, const int* __restrict__ list,
    int* __restrict__ hist, int H, int K, int cap) {
  if (cap <= 0) return;
  __shared__ float xs[4096];
  __shared__ double red[256];
  const int tid = threadIdx.x;
  const int n = min(*cnt, cap);
  for (int idx = blockIdx.x; idx < n; idx += gridDim.x) {
    const int t = list[idx];
    for (int i = tid; i < H / 4; i += 256)
      reinterpret_cast<float4*>(xs)[i] =
          reinterpret_cast<const float4*>(X + (size_t)t * H)[i];
    __syncthreads();
    const int e = tid & 63, sl = tid >> 6;
    const float* wr = W + (size_t)e * H + sl * (H / 4);
    const float* xr = xs + sl * (H / 4);
    double acc = 0.0;
    for (int k = 0; k < H / 4; k += 4) {
      const float4 wv = *reinterpret_cast<const float4*>(wr + k);
      const float4 xv = *reinterpret_cast<const float4*>(xr + k);
      acc = fma((double)xv.x, (double)wv.x, acc);
      acc = fma((double)xv.y, (double)wv.y, acc);
      acc = fma((double)xv.z, (double)wv.z, acc);
      acc = fma((double)xv.w, (double)wv.w, acc);
    }
    red[tid] = acc;
    __syncthreads();
    if (tid < 64) {
      double s =
          red[e] + red[64 + e] + red[128 + e] + red[192 + e] + (double)bias[e];
      double m = s;
#pragma unroll
      for (int off = 32; off >= 1; off >>= 1) m = fmax(m, __shfl_xor(m, off));
      const double ex = exp(s - m);
      double sum = ex;
#pragma unroll
      for (int off = 32; off >= 1; off >>= 1) sum += __shfl_xor(sum, off);
      const double p = ex / sum;
      S[(size_t)t * NE + e] = (float)p;
      double wsel = s;
      double rv = 0.0;
      int ri = 0;
      for (int r = 0; r < K; ++r) {
        double v = wsel;
        int ii = e;
#pragma unroll
        for (int off = 32; off >= 1; off >>= 1) {
          const double ov = __shfl_xor(v, off);
          const int oi = __shfl_xor(ii, off);
          if (ov > v || (ov == v && oi < ii)) { v = ov; ii = oi; }
        }
        const double pw = __shfl(p, ii);
        if (e == r) { rv = pw; ri = ii; }
        if (e == ii) wsel = -1e300;
      }
      if (e < K) {
        wout[(size_t)t * K + e] = (float)rv;
        iout[(size_t)t * K + e] = (float)ri;
        atomicAdd(&hist[ri], 1);
      }
    }
    __syncthreads();
  }
}

// ------------- Kernel D: bias update from integer histogram -----------------
__global__ void bias_update(const int* __restrict__ hist,
                            const float* __restrict__ bias,
                            float* __restrict__ bout, float tpe) {
  const int e = threadIdx.x;
  const float d = (float)hist[e] - tpe;
  const float sg = (d > 0.f) ? 1.f : ((d < 0.f) ? -1.f : 0.f);
  bout[e] = bias[e] + 0.01f * sg;
}

extern "C" void kernel_launch(void* const* d_in, const int* in_sizes, int n_in,
                              void* d_out, int out_size, void* d_ws, size_t ws_size,
                              hipStream_t stream) {
  const float* x = (const float*)d_in[0];
  const float* w = (const float*)d_in[1];
  const float* bias = (const float*)d_in[2];
  const int E = in_sizes[2];                       // 64
  const int H = in_sizes[1] / E;                   // 4096
  const long long N = (long long)in_sizes[0] / H;  // 32768 tokens
  const int K = (int)(((long long)out_size - N * E - E) / (2 * N));  // 8

  float* S = (float*)d_out;                 // [N][E] probs (raw scores first)
  float* wout = S + (size_t)N * E;          // [N][K]
  float* iout = wout + (size_t)N * K;       // [N][K] indices as float
  float* bout = iout + (size_t)N * K;       // [E]

  // workspace layout: [0,4) count | [256,512) int hist | [1024,..) token list
  // | [1MB,..) optional K-split partial
  int* cnt = (int*)d_ws;
  int* hist = (int*)d_ws + 64;
  int* list = (int*)d_ws + 256;
  const size_t P2OFF = (size_t)1 << 20;
  float* P2 = (float*)((char*)d_ws + P2OFF);
  const size_t p2need = P2OFF + (size_t)N * E * sizeof(float);
  const int ksplit = (ws_size >= p2need) ? 2 : 1;
  int cap = 0;
  if (ws_size >= 4096) {
    const size_t limit = (ksplit == 2) ? P2OFF : ws_size;
    cap = (int)min((size_t)131072, (limit - 1024) / 4);
  }
  if (ws_size >= 512) hipMemsetAsync(d_ws, 0, 512, stream);

  gemm_f32<<<dim3((int)(N / BM), ksplit), 256, 0, stream>>>(x, w, S, P2, H,
                                                            ksplit);
  softmax_topk<<<dim3((int)(N / 64)), 256, 0, stream>>>(
      S, P2, ksplit - 1, bias, wout, iout, cnt, hist, list, cap, K);
  recompute_f64<<<dim3(256), 256, 0, stream>>>(x, w, bias, S, wout, iout, cnt,
                                               list, hist, H, K, cap);
  bias_update<<<dim3(1), dim3(E), 0, stream>>>(hist, bias, bout,
                                               (float)((double)N * K / E));
}